// Round 18
// baseline (279.632 us; speedup 1.0000x reference)
//
#include <hip/hip_runtime.h>
#include <stdint.h>

typedef unsigned short u16;
typedef __bf16 bf16x8 __attribute__((ext_vector_type(8)));
typedef float  f32x4  __attribute__((ext_vector_type(4)));

// ---- problem constants ----
#define SDIM 2048
#define BDIM 8
#define DIN  1024
#define DOUT 4096
#define EDIM 8
#define RDIM 16
#define KAUG 1152            // DIN + E*R
#define MDIM (SDIM*BDIM)     // 16384
#define SCH  64              // R17: 512 blocks (2/CU) for k1 BW
#define NT2  18              // K-tiles of 64 for the main GEMM

__device__ __forceinline__ u16 f2bf(float f) {
    __bf16 h = (__bf16)f;
    return __builtin_bit_cast(u16, h);
}

__device__ __forceinline__ void gload16(const u16* g, u16* lds) {
    __builtin_amdgcn_global_load_lds(
        (const __attribute__((address_space(1))) void*)g,
        (__attribute__((address_space(3))) void*)lds, 16, 0, 0);
}

#define VMCNT(n)  asm volatile("s_waitcnt vmcnt(" #n ")" ::: "memory")
#define BARF()    do { asm volatile("" ::: "memory");                \
                       __builtin_amdgcn_s_barrier();                 \
                       asm volatile("" ::: "memory"); } while (0)

// ---------------------------------------------------------------------------
// k1: per-(b, s-chunk) partial sums of x over s + bf16 convert into Xb
// grid (BDIM, SCH=64), 256 thr -> 512 blocks = 2/CU (memory-bound TLP).
// ---------------------------------------------------------------------------
__global__ __launch_bounds__(256) void k1_reduce_convert(
    const float* __restrict__ x, u16* __restrict__ Xb, float* __restrict__ P)
{
    const int b  = blockIdx.x;
    const int sc = blockIdx.y;
    const int i  = threadIdx.x * 4;
    float a0 = 0.f, a1 = 0.f, a2 = 0.f, a3 = 0.f;
    const int s0 = sc * (SDIM / SCH);
    for (int s = s0; s < s0 + (SDIM / SCH); ++s) {
        const float4 v = *reinterpret_cast<const float4*>(
            &x[((size_t)s * BDIM + b) * DIN + i]);
        a0 += v.x; a1 += v.y; a2 += v.z; a3 += v.w;
        ushort4 u{f2bf(v.x), f2bf(v.y), f2bf(v.z), f2bf(v.w)};
        *reinterpret_cast<ushort4*>(&Xb[((size_t)s * BDIM + b) * KAUG + i]) = u;
    }
    float4 p{a0, a1, a2, a3};
    *reinterpret_cast<float4*>(&P[((size_t)sc * BDIM + b) * DIN + i]) = p;
}

// ---------------------------------------------------------------------------
// kprep2 (R17): fused Waug build + lora_A convert + gate weights.
// Launched AFTER k1 -> P is complete for the gate branch.
//   blocks [0, DOUT):            Waug row o
//   blocks [DOUT, DOUT+512):     LAb chunk
//   blocks [DOUT+512, +64):      gate (e,b)
// ---------------------------------------------------------------------------
__global__ __launch_bounds__(256) void kprep2(
    const float* __restrict__ W, const float* __restrict__ lb,
    const float* __restrict__ la, const float* __restrict__ P,
    const float* __restrict__ gw, const float* __restrict__ gb,
    u16* __restrict__ Waug, u16* __restrict__ LAb, float* __restrict__ g)
{
    const int bidx = blockIdx.x, t = threadIdx.x;
    if (bidx < DOUT) {
        const int o = bidx;
        for (int i = t; i < DIN; i += 256)
            Waug[(size_t)o * KAUG + i] = f2bf(W[(size_t)o * DIN + i]);
        if (t < EDIM * RDIM) {
            const int e = t >> 4, r = t & 15;
            Waug[(size_t)o * KAUG + DIN + t] =
                f2bf(lb[((size_t)e * DOUT + o) * RDIM + r]);
        }
    } else if (bidx < DOUT + 512) {
        const int idx = (bidx - DOUT) * 256 + t;
        if (idx < EDIM * RDIM * DIN) LAb[idx] = f2bf(la[idx]);
    } else {
        const int b2 = bidx - DOUT - 512;   // 0..63
        const int e = b2 & 7, b = b2 >> 3;
        float dot = 0.f;
        for (int i = t; i < DIN; i += 256) {
            float xs = 0.f;
            #pragma unroll
            for (int c = 0; c < SCH; ++c)
                xs += P[((size_t)c * BDIM + b) * DIN + i];
            dot += xs * gw[(size_t)e * DIN + i];
        }
        __shared__ float red[256];
        red[t] = dot;
        __syncthreads();
        #pragma unroll
        for (int off = 128; off > 0; off >>= 1) {
            if (t < off) red[t] += red[t + off];
            __syncthreads();
        }
        if (t == 0) g[b * EDIM + e] = red[0] * (1.0f / SDIM) + gb[e];
    }
}

// ---------------------------------------------------------------------------
// gemm_lora2: t = Xb(:, :1024) * LAb^T with fused u = bf16(g*t) epilogue
// written into Xb cols [1024,1152). Tile M=64 x N=128, grid 256 blocks,
// 256 thr / 4 waves (2M x 2N, per-wave 32x64). R6 coalesced+XOR LDS layout.
// LDS 24KB -> multiple blocks/CU. Reads cols <1024, writes >=1024: no race.
// (R16-verified: total 238.9 -> 231.4 with this + prep fusion.)
// ---------------------------------------------------------------------------
__global__ __launch_bounds__(256) void gemm_lora2(
    const u16* __restrict__ A, const u16* __restrict__ B,
    const float* __restrict__ G, u16* __restrict__ Xb)
{
    __shared__ __align__(16) u16 As[64][64];     // 8 KB
    __shared__ __align__(16) u16 Bs[128][64];    // 16 KB

    const int tid  = threadIdx.x;
    const int lane = tid & 63;
    const int l15  = lane & 15;
    const int l4   = lane >> 4;
    const int sw   = lane & 7;
    const int wid  = tid >> 6;      // 0..3
    const int wr   = wid >> 1;      // 0..1 (32-row slice)
    const int wc   = wid & 1;       // 0..1 (64-col slice)
    const int m0 = blockIdx.y * 64;

    f32x4 acc[2][4] = {};

    for (int kt = 0; kt < DIN / 64; ++kt) {
        #pragma unroll
        for (int ii = 0; ii < 2; ++ii) {
            const int cix = ii * 256 + tid;
            const int row = cix >> 3, cl = cix & 7;
            const int kof = kt * 64 + ((cl ^ (row & 7)) << 3);
            gload16(A + (size_t)(m0 + row) * KAUG + kof, &As[0][0] + cix * 8);
        }
        #pragma unroll
        for (int ii = 0; ii < 4; ++ii) {
            const int cix = ii * 256 + tid;
            const int row = cix >> 3, cl = cix & 7;
            const int kof = kt * 64 + ((cl ^ (row & 7)) << 3);
            gload16(B + (size_t)row * DIN + kof, &Bs[0][0] + cix * 8);
        }
        __syncthreads();
        #pragma unroll
        for (int ks = 0; ks < 2; ++ks) {
            bf16x8 av[2], bv[4];
            #pragma unroll
            for (int mi = 0; mi < 2; ++mi)
                av[mi] = *reinterpret_cast<const bf16x8*>(
                    &As[wr * 32 + mi * 16 + l15][((ks * 4 + l4) ^ sw) << 3]);
            #pragma unroll
            for (int ni = 0; ni < 4; ++ni)
                bv[ni] = *reinterpret_cast<const bf16x8*>(
                    &Bs[wc * 64 + ni * 16 + l15][((ks * 4 + l4) ^ sw) << 3]);
            #pragma unroll
            for (int mi = 0; mi < 2; ++mi)
                #pragma unroll
                for (int ni = 0; ni < 4; ++ni)
                    acc[mi][ni] = __builtin_amdgcn_mfma_f32_16x16x32_bf16(
                        av[mi], bv[ni], acc[mi][ni], 0, 0, 0);
        }
        __syncthreads();
    }

    #pragma unroll
    for (int mi = 0; mi < 2; ++mi) {
        const int r0 = m0 + wr * 32 + mi * 16 + l4 * 4;
        #pragma unroll
        for (int ni = 0; ni < 4; ++ni) {
            const int col = wc * 64 + ni * 16 + l15;   // 0..127
            const int e   = col >> 4;
            #pragma unroll
            for (int r = 0; r < 4; ++r) {
                const int row = r0 + r;
                const float gv = G[((row & 7) << 3) + e];
                Xb[(size_t)row * KAUG + DIN + col] = f2bf(gv * acc[mi][ni][r]);
            }
        }
    }
}

// ---------------------------------------------------------------------------
// gemm_main (FROZEN, best measured: 168-170 us, 909 TF): R8 4-phase
// 1-barrier counted-vmcnt schedule + coalesced staging + (row&7) chunk-XOR
// swizzle + supertile XCD mapping (FETCH 166->110 MB).
// BM=BN=256, BK=64, NT2=18, 512 thr (8 waves 2Mx4N), dbuf LDS 128 KiB.
// Variants measured and rejected: R9 read-ahead 170, R10 2-barrier 178,
// R13 deep-lead 186, R14 B-in-regs 187, R15 min-sync 194.
// ---------------------------------------------------------------------------
__global__ __launch_bounds__(512) void gemm_main(
    const u16* __restrict__ A, const u16* __restrict__ Bm,
    float* __restrict__ C, const float* __restrict__ bias)
{
    __shared__ __align__(16) u16 As[2][2][128][64];   // [buf][Mhalf][row][k] 64 KiB
    __shared__ __align__(16) u16 Bs[2][2][128][64];   // [buf][Nhalf][row][k] 64 KiB

    const int tid  = threadIdx.x;
    const int lane = tid & 63;
    const int l15  = lane & 15;
    const int l4   = lane >> 4;
    const int sw   = lane & 7;
    const int wid  = tid >> 6;      // 0..7
    const int wm   = wid >> 2;      // 0..1  (128-row half)
    const int wn   = wid & 3;       // 0..3  (64-col quarter)
    const int bh   = wn >> 1;       // B Nhalf
    const int bl   = wn & 1;        // 64-row block within half

    // supertile XCD mapping (R12-verified)
    const int f   = blockIdx.x + blockIdx.y * gridDim.x;
    const int xcd = f & 7, k = f >> 3;
    const int gn  = xcd & 3, gm = xcd >> 2;
    const int n0  = (gn * 4 + (k & 3)) * 256;
    const int m0  = (gm * 32 + (k >> 2)) * 256;

    f32x4  acc[8][4] = {};
    bf16x8 aq[2][2], bv[4][2];

    auto stage = [&](int s) {
        const int t = s >> 2, part = s & 3, buf = t & 1, hf = part & 1;
        #pragma unroll
        for (int ii = 0; ii < 2; ++ii) {
            const int cix = ii * 512 + tid;
            const int row = cix >> 3, cl = cix & 7;
            const int kof = t * 64 + ((cl ^ (row & 7)) << 3);
            if (part < 2)
                gload16(A + (size_t)(m0 + hf * 128 + row) * KAUG + kof,
                        &As[buf][hf][0][0] + cix * 8);
            else
                gload16(Bm + (size_t)(n0 + hf * 128 + row) * KAUG + kof,
                        &Bs[buf][hf][0][0] + cix * 8);
        }
    };

    // prologue: units 0..4 (tile 0 fully + A-h0 of tile 1) = 10 gloads
    stage(0); stage(1); stage(2); stage(3); stage(4);
    VMCNT(2);                       // confirm units 0..3 (tile 0); unit 4 in flight
    BARF();

    #define PHASE(P)                                                            \
    do {                                                                        \
        if ((P) == 0) {                                                         \
            _Pragma("unroll") for (int nf = 0; nf < 4; ++nf)                    \
                _Pragma("unroll") for (int kk = 0; kk < 2; ++kk)                \
                    bv[nf][kk] = *reinterpret_cast<const bf16x8*>(              \
                        &Bs[buf][bh][bl * 64 + nf * 16 + l15]                   \
                           [((kk * 4 + l4) ^ sw) << 3]);                        \
        }                                                                       \
        _Pragma("unroll") for (int fr = 0; fr < 2; ++fr)                        \
            _Pragma("unroll") for (int kk = 0; kk < 2; ++kk)                    \
                aq[fr][kk] = *reinterpret_cast<const bf16x8*>(                  \
                    &As[buf][wm][(P) * 32 + fr * 16 + l15]                      \
                       [((kk * 4 + l4) ^ sw) << 3]);                            \
        { const int su = 4 * j + 5 + (P); if (su < 4 * NT2) stage(su); }        \
        __builtin_amdgcn_s_setprio(1);                                          \
        _Pragma("unroll") for (int kk = 0; kk < 2; ++kk)                        \
            _Pragma("unroll") for (int fr = 0; fr < 2; ++fr)                    \
                _Pragma("unroll") for (int nf = 0; nf < 4; ++nf)                \
                    acc[(P) * 2 + fr][nf] =                                     \
                        __builtin_amdgcn_mfma_f32_16x16x32_bf16(                \
                            aq[fr][kk], bv[nf][kk], acc[(P) * 2 + fr][nf],      \
                            0, 0, 0);                                           \
        __builtin_amdgcn_s_setprio(0);                                          \
        if ((P) == 3) { if (j < NT2 - 2) VMCNT(2); else VMCNT(0); }             \
        BARF();                                                                 \
    } while (0)

    for (int j = 0; j < NT2; ++j) {
        const int buf = j & 1;
        PHASE(0);
        PHASE(1);
        PHASE(2);
        PHASE(3);
    }
    #undef PHASE

    // ---- epilogue: row = wm*128 + a*16 + l4*4, col per fragment ----
    #pragma unroll
    for (int a = 0; a < 8; ++a) {
        const int row0 = m0 + wm * 128 + a * 16 + l4 * 4;
        #pragma unroll
        for (int nf = 0; nf < 4; ++nf) {
            const int col = n0 + wn * 64 + nf * 16 + l15;
            const float badd = bias[col];
            float* cp = C + (size_t)row0 * DOUT + col;
            #pragma unroll
            for (int q = 0; q < 4; ++q)
                cp[(size_t)q * DOUT] = acc[a][nf][q] + badd;
        }
    }
}

// ---------------------------------------------------------------------------
extern "C" void kernel_launch(void* const* d_in, const int* in_sizes, int n_in,
                              void* d_out, int out_size, void* d_ws, size_t ws_size,
                              hipStream_t stream)
{
    const float* x    = (const float*)d_in[0];
    const float* gw   = (const float*)d_in[1];
    const float* gb   = (const float*)d_in[2];
    const float* W    = (const float*)d_in[3];
    const float* bias = (const float*)d_in[4];
    const float* la   = (const float*)d_in[5];
    const float* lb   = (const float*)d_in[6];
    float* out = (float*)d_out;

    char* ws = (char*)d_ws;
    u16*   Xb   = (u16*)(ws);                       // 37,748,736 B
    u16*   Waug = (u16*)(ws + 37748736);            //  9,437,184 B
    float* P    = (float*)(ws + 47185920);          //  2,097,152 B (SCH=64)
    u16*   LAb  = (u16*)(ws + 49283072);            //    262,144 B
    float* G    = (float*)(ws + 49545216);          //        256 B

    // 1) reduce+convert x (512 blocks = 2/CU)
    k1_reduce_convert<<<dim3(BDIM, SCH), 256, 0, stream>>>(x, Xb, P);
    // 2) fused prep: Waug + LAb + gates (after k1 -> P complete)
    kprep2<<<DOUT + 512 + EDIM * BDIM, 256, 0, stream>>>(
        W, lb, la, P, gw, gb, Waug, LAb, G);
    // 3) LoRA GEMM with fused g-scale epilogue
    gemm_lora2<<<dim3(1, MDIM / 64), 256, 0, stream>>>(Xb, LAb, G, Xb);
    // 4) main GEMM (frozen)
    gemm_main<<<dim3(DOUT / 256, MDIM / 256), 512, 0, stream>>>(
        Xb, Waug, out, bias);
}

// Round 19
// 232.159 us; speedup vs baseline: 1.2045x; 1.2045x over previous
//
#include <hip/hip_runtime.h>
#include <stdint.h>

typedef unsigned short u16;
typedef __bf16 bf16x8 __attribute__((ext_vector_type(8)));
typedef float  f32x4  __attribute__((ext_vector_type(4)));

// ---- problem constants ----
#define SDIM 2048
#define BDIM 8
#define DIN  1024
#define DOUT 4096
#define EDIM 8
#define RDIM 16
#define KAUG 1152            // DIN + E*R
#define MDIM (SDIM*BDIM)     // 16384
#define SCH  32
#define NT2  18              // K-tiles of 64 for the main GEMM

__device__ __forceinline__ u16 f2bf(float f) {
    __bf16 h = (__bf16)f;
    return __builtin_bit_cast(u16, h);
}

__device__ __forceinline__ void gload16(const u16* g, u16* lds) {
    __builtin_amdgcn_global_load_lds(
        (const __attribute__((address_space(1))) void*)g,
        (__attribute__((address_space(3))) void*)lds, 16, 0, 0);
}

#define VMCNT(n)  asm volatile("s_waitcnt vmcnt(" #n ")" ::: "memory")
#define BARF()    do { asm volatile("" ::: "memory");                \
                       __builtin_amdgcn_s_barrier();                 \
                       asm volatile("" ::: "memory"); } while (0)

// ---------------------------------------------------------------------------
// k1: per-(b, s-chunk) partial sums of x over s + bf16 convert into Xb
// ---------------------------------------------------------------------------
__global__ __launch_bounds__(256) void k1_reduce_convert(
    const float* __restrict__ x, u16* __restrict__ Xb, float* __restrict__ P)
{
    const int b  = blockIdx.x;
    const int sc = blockIdx.y;
    const int i  = threadIdx.x * 4;
    float a0 = 0.f, a1 = 0.f, a2 = 0.f, a3 = 0.f;
    const int s0 = sc * (SDIM / SCH);
    for (int s = s0; s < s0 + (SDIM / SCH); ++s) {
        const float4 v = *reinterpret_cast<const float4*>(
            &x[((size_t)s * BDIM + b) * DIN + i]);
        a0 += v.x; a1 += v.y; a2 += v.z; a3 += v.w;
        ushort4 u{f2bf(v.x), f2bf(v.y), f2bf(v.z), f2bf(v.w)};
        *reinterpret_cast<ushort4*>(&Xb[((size_t)s * BDIM + b) * KAUG + i]) = u;
    }
    float4 p{a0, a1, a2, a3};
    *reinterpret_cast<float4*>(&P[((size_t)sc * BDIM + b) * DIN + i]) = p;
}

// ---------------------------------------------------------------------------
// k2: gate weights
// ---------------------------------------------------------------------------
__global__ __launch_bounds__(256) void k2_gates(
    const float* __restrict__ P, const float* __restrict__ gw,
    const float* __restrict__ gb, float* __restrict__ g)
{
    const int e = blockIdx.x, b = blockIdx.y, t = threadIdx.x;
    float dot = 0.f;
    for (int i = t; i < DIN; i += 256) {
        float xs = 0.f;
        #pragma unroll
        for (int c = 0; c < SCH; ++c) xs += P[((size_t)c * BDIM + b) * DIN + i];
        dot += xs * gw[(size_t)e * DIN + i];
    }
    __shared__ float red[256];
    red[t] = dot;
    __syncthreads();
    #pragma unroll
    for (int off = 128; off > 0; off >>= 1) {
        if (t < off) red[t] += red[t + off];
        __syncthreads();
    }
    if (t == 0) g[b * EDIM + e] = red[0] * (1.0f / SDIM) + gb[e];
}

// ---------------------------------------------------------------------------
// kwkl: fused Waug build + lora_A convert (one launch).
//   blocks [0, DOUT): Waug row o  |  blocks [DOUT, DOUT+512): LAb chunk
// ---------------------------------------------------------------------------
__global__ __launch_bounds__(256) void kwkl_build(
    const float* __restrict__ W, const float* __restrict__ lb,
    const float* __restrict__ la, u16* __restrict__ Waug, u16* __restrict__ LAb)
{
    const int bidx = blockIdx.x, t = threadIdx.x;
    if (bidx < DOUT) {
        const int o = bidx;
        for (int i = t; i < DIN; i += 256)
            Waug[(size_t)o * KAUG + i] = f2bf(W[(size_t)o * DIN + i]);
        if (t < EDIM * RDIM) {
            const int e = t >> 4, r = t & 15;
            Waug[(size_t)o * KAUG + DIN + t] =
                f2bf(lb[((size_t)e * DOUT + o) * RDIM + r]);
        }
    } else {
        const int idx = (bidx - DOUT) * 256 + t;
        if (idx < EDIM * RDIM * DIN) LAb[idx] = f2bf(la[idx]);
    }
}

// ---------------------------------------------------------------------------
// gemm_lora2: t = Xb(:, :1024) * LAb^T with fused u = bf16(g*t) epilogue
// written into Xb cols [1024,1152). Tile M=64 x N=128, grid 256 blocks,
// 256 thr / 4 waves (2M x 2N, per-wave 32x64). R6 coalesced+XOR LDS layout.
// LDS 24KB -> multiple blocks/CU. Reads cols <1024, writes >=1024: no race.
// (R16-verified: total 238.9 -> 231.4 with this + prep fusion.)
// ---------------------------------------------------------------------------
__global__ __launch_bounds__(256) void gemm_lora2(
    const u16* __restrict__ A, const u16* __restrict__ B,
    const float* __restrict__ G, u16* __restrict__ Xb)
{
    __shared__ __align__(16) u16 As[64][64];     // 8 KB
    __shared__ __align__(16) u16 Bs[128][64];    // 16 KB

    const int tid  = threadIdx.x;
    const int lane = tid & 63;
    const int l15  = lane & 15;
    const int l4   = lane >> 4;
    const int sw   = lane & 7;
    const int wid  = tid >> 6;      // 0..3
    const int wr   = wid >> 1;      // 0..1 (32-row slice)
    const int wc   = wid & 1;       // 0..1 (64-col slice)
    const int m0 = blockIdx.y * 64;

    f32x4 acc[2][4] = {};

    for (int kt = 0; kt < DIN / 64; ++kt) {
        #pragma unroll
        for (int ii = 0; ii < 2; ++ii) {
            const int cix = ii * 256 + tid;
            const int row = cix >> 3, cl = cix & 7;
            const int kof = kt * 64 + ((cl ^ (row & 7)) << 3);
            gload16(A + (size_t)(m0 + row) * KAUG + kof, &As[0][0] + cix * 8);
        }
        #pragma unroll
        for (int ii = 0; ii < 4; ++ii) {
            const int cix = ii * 256 + tid;
            const int row = cix >> 3, cl = cix & 7;
            const int kof = kt * 64 + ((cl ^ (row & 7)) << 3);
            gload16(B + (size_t)row * DIN + kof, &Bs[0][0] + cix * 8);
        }
        __syncthreads();
        #pragma unroll
        for (int ks = 0; ks < 2; ++ks) {
            bf16x8 av[2], bv[4];
            #pragma unroll
            for (int mi = 0; mi < 2; ++mi)
                av[mi] = *reinterpret_cast<const bf16x8*>(
                    &As[wr * 32 + mi * 16 + l15][((ks * 4 + l4) ^ sw) << 3]);
            #pragma unroll
            for (int ni = 0; ni < 4; ++ni)
                bv[ni] = *reinterpret_cast<const bf16x8*>(
                    &Bs[wc * 64 + ni * 16 + l15][((ks * 4 + l4) ^ sw) << 3]);
            #pragma unroll
            for (int mi = 0; mi < 2; ++mi)
                #pragma unroll
                for (int ni = 0; ni < 4; ++ni)
                    acc[mi][ni] = __builtin_amdgcn_mfma_f32_16x16x32_bf16(
                        av[mi], bv[ni], acc[mi][ni], 0, 0, 0);
        }
        __syncthreads();
    }

    #pragma unroll
    for (int mi = 0; mi < 2; ++mi) {
        const int r0 = m0 + wr * 32 + mi * 16 + l4 * 4;
        #pragma unroll
        for (int ni = 0; ni < 4; ++ni) {
            const int col = wc * 64 + ni * 16 + l15;   // 0..127
            const int e   = col >> 4;
            #pragma unroll
            for (int r = 0; r < 4; ++r) {
                const int row = r0 + r;
                const float gv = G[((row & 7) << 3) + e];
                Xb[(size_t)row * KAUG + DIN + col] = f2bf(gv * acc[mi][ni][r]);
            }
        }
    }
}

// ---------------------------------------------------------------------------
// gemm_main (FROZEN, best measured: 168-170 us, 909 TF): R8 4-phase
// 1-barrier counted-vmcnt schedule + coalesced staging + (row&7) chunk-XOR
// swizzle + supertile XCD mapping (FETCH 166->110 MB).
// BM=BN=256, BK=64, NT2=18, 512 thr (8 waves 2Mx4N), dbuf LDS 128 KiB.
// Variants measured and rejected: R9 read-ahead 170, R10 2-barrier 178,
// R13 deep-lead 186, R14 B-in-regs 187, R15 min-sync 194.
// ---------------------------------------------------------------------------
__global__ __launch_bounds__(512) void gemm_main(
    const u16* __restrict__ A, const u16* __restrict__ Bm,
    float* __restrict__ C, const float* __restrict__ bias)
{
    __shared__ __align__(16) u16 As[2][2][128][64];   // [buf][Mhalf][row][k] 64 KiB
    __shared__ __align__(16) u16 Bs[2][2][128][64];   // [buf][Nhalf][row][k] 64 KiB

    const int tid  = threadIdx.x;
    const int lane = tid & 63;
    const int l15  = lane & 15;
    const int l4   = lane >> 4;
    const int sw   = lane & 7;
    const int wid  = tid >> 6;      // 0..7
    const int wm   = wid >> 2;      // 0..1  (128-row half)
    const int wn   = wid & 3;       // 0..3  (64-col quarter)
    const int bh   = wn >> 1;       // B Nhalf
    const int bl   = wn & 1;        // 64-row block within half

    // supertile XCD mapping (R12-verified)
    const int f   = blockIdx.x + blockIdx.y * gridDim.x;
    const int xcd = f & 7, k = f >> 3;
    const int gn  = xcd & 3, gm = xcd >> 2;
    const int n0  = (gn * 4 + (k & 3)) * 256;
    const int m0  = (gm * 32 + (k >> 2)) * 256;

    f32x4  acc[8][4] = {};
    bf16x8 aq[2][2], bv[4][2];

    auto stage = [&](int s) {
        const int t = s >> 2, part = s & 3, buf = t & 1, hf = part & 1;
        #pragma unroll
        for (int ii = 0; ii < 2; ++ii) {
            const int cix = ii * 512 + tid;
            const int row = cix >> 3, cl = cix & 7;
            const int kof = t * 64 + ((cl ^ (row & 7)) << 3);
            if (part < 2)
                gload16(A + (size_t)(m0 + hf * 128 + row) * KAUG + kof,
                        &As[buf][hf][0][0] + cix * 8);
            else
                gload16(Bm + (size_t)(n0 + hf * 128 + row) * KAUG + kof,
                        &Bs[buf][hf][0][0] + cix * 8);
        }
    };

    // prologue: units 0..4 (tile 0 fully + A-h0 of tile 1) = 10 gloads
    stage(0); stage(1); stage(2); stage(3); stage(4);
    VMCNT(2);                       // confirm units 0..3 (tile 0); unit 4 in flight
    BARF();

    #define PHASE(P)                                                            \
    do {                                                                        \
        if ((P) == 0) {                                                         \
            _Pragma("unroll") for (int nf = 0; nf < 4; ++nf)                    \
                _Pragma("unroll") for (int kk = 0; kk < 2; ++kk)                \
                    bv[nf][kk] = *reinterpret_cast<const bf16x8*>(              \
                        &Bs[buf][bh][bl * 64 + nf * 16 + l15]                   \
                           [((kk * 4 + l4) ^ sw) << 3]);                        \
        }                                                                       \
        _Pragma("unroll") for (int fr = 0; fr < 2; ++fr)                        \
            _Pragma("unroll") for (int kk = 0; kk < 2; ++kk)                    \
                aq[fr][kk] = *reinterpret_cast<const bf16x8*>(                  \
                    &As[buf][wm][(P) * 32 + fr * 16 + l15]                      \
                       [((kk * 4 + l4) ^ sw) << 3]);                            \
        { const int su = 4 * j + 5 + (P); if (su < 4 * NT2) stage(su); }        \
        __builtin_amdgcn_s_setprio(1);                                          \
        _Pragma("unroll") for (int kk = 0; kk < 2; ++kk)                        \
            _Pragma("unroll") for (int fr = 0; fr < 2; ++fr)                    \
                _Pragma("unroll") for (int nf = 0; nf < 4; ++nf)                \
                    acc[(P) * 2 + fr][nf] =                                     \
                        __builtin_amdgcn_mfma_f32_16x16x32_bf16(                \
                            aq[fr][kk], bv[nf][kk], acc[(P) * 2 + fr][nf],      \
                            0, 0, 0);                                           \
        __builtin_amdgcn_s_setprio(0);                                          \
        if ((P) == 3) { if (j < NT2 - 2) VMCNT(2); else VMCNT(0); }             \
        BARF();                                                                 \
    } while (0)

    for (int j = 0; j < NT2; ++j) {
        const int buf = j & 1;
        PHASE(0);
        PHASE(1);
        PHASE(2);
        PHASE(3);
    }
    #undef PHASE

    // ---- epilogue: row = wm*128 + a*16 + l4*4, col per fragment ----
    #pragma unroll
    for (int a = 0; a < 8; ++a) {
        const int row0 = m0 + wm * 128 + a * 16 + l4 * 4;
        #pragma unroll
        for (int nf = 0; nf < 4; ++nf) {
            const int col = n0 + wn * 64 + nf * 16 + l15;
            const float badd = bias[col];
            float* cp = C + (size_t)row0 * DOUT + col;
            #pragma unroll
            for (int q = 0; q < 4; ++q)
                cp[(size_t)q * DOUT] = acc[a][nf][q] + badd;
        }
    }
}

// ---------------------------------------------------------------------------
extern "C" void kernel_launch(void* const* d_in, const int* in_sizes, int n_in,
                              void* d_out, int out_size, void* d_ws, size_t ws_size,
                              hipStream_t stream)
{
    const float* x    = (const float*)d_in[0];
    const float* gw   = (const float*)d_in[1];
    const float* gb   = (const float*)d_in[2];
    const float* W    = (const float*)d_in[3];
    const float* bias = (const float*)d_in[4];
    const float* la   = (const float*)d_in[5];
    const float* lb   = (const float*)d_in[6];
    float* out = (float*)d_out;

    char* ws = (char*)d_ws;
    u16*   Xb   = (u16*)(ws);                       // 37,748,736 B
    u16*   Waug = (u16*)(ws + 37748736);            //  9,437,184 B
    float* P    = (float*)(ws + 47185920);          //  1,048,576 B
    u16*   LAb  = (u16*)(ws + 48234496);            //    262,144 B
    float* G    = (float*)(ws + 48496640);          //        256 B

    k1_reduce_convert<<<dim3(BDIM, SCH), 256, 0, stream>>>(x, Xb, P);
    kwkl_build<<<DOUT + (EDIM * RDIM * DIN + 255) / 256, 256, 0, stream>>>(
        W, lb, la, Waug, LAb);
    k2_gates<<<dim3(EDIM, BDIM), 256, 0, stream>>>(P, gw, gb, G);
    gemm_lora2<<<dim3(1, MDIM / 64), 256, 0, stream>>>(Xb, LAb, G, Xb);
    gemm_main<<<dim3(DOUT / 256, MDIM / 256), 512, 0, stream>>>(
        Xb, Waug, out, bias);
}

// Round 20
// 223.712 us; speedup vs baseline: 1.2500x; 1.0378x over previous
//
#include <hip/hip_runtime.h>
#include <stdint.h>

typedef unsigned short u16;
typedef __bf16 bf16x8 __attribute__((ext_vector_type(8)));
typedef float  f32x4  __attribute__((ext_vector_type(4)));

// ---- problem constants ----
#define SDIM 2048
#define BDIM 8
#define DIN  1024
#define DOUT 4096
#define EDIM 8
#define RDIM 16
#define KAUG 1152            // DIN + E*R
#define MDIM (SDIM*BDIM)     // 16384
#define SCH  32
#define NT2  18              // K-tiles of 64 for the main GEMM

__device__ __forceinline__ u16 f2bf(float f) {
    __bf16 h = (__bf16)f;
    return __builtin_bit_cast(u16, h);
}

__device__ __forceinline__ void gload16(const u16* g, u16* lds) {
    __builtin_amdgcn_global_load_lds(
        (const __attribute__((address_space(1))) void*)g,
        (__attribute__((address_space(3))) void*)lds, 16, 0, 0);
}

#define VMCNT(n)  asm volatile("s_waitcnt vmcnt(" #n ")" ::: "memory")
#define BARF()    do { asm volatile("" ::: "memory");                \
                       __builtin_amdgcn_s_barrier();                 \
                       asm volatile("" ::: "memory"); } while (0)

// ---------------------------------------------------------------------------
// kprep (R19): fused k1 (x reduce+convert) + kwkl (Waug build + LAb convert).
// The two halves are INDEPENDENT (kwkl touches neither x nor P); k2 (which
// consumes P) remains a separate, later launch. Both branches are low-VGPR,
// so the R17 regalloc-max hazard doesn't apply.
//   blocks [0, 256):            k1: b = bidx&7, sc = bidx>>3  (8x32 remap)
//   blocks [256, 256+DOUT):     Waug row o
//   blocks [256+DOUT, +512):    LAb chunk
// ---------------------------------------------------------------------------
__global__ __launch_bounds__(256) void kprep(
    const float* __restrict__ x, u16* __restrict__ Xb, float* __restrict__ P,
    const float* __restrict__ W, const float* __restrict__ lb,
    const float* __restrict__ la, u16* __restrict__ Waug, u16* __restrict__ LAb)
{
    const int bidx = blockIdx.x, t = threadIdx.x;
    if (bidx < 256) {
        // ---- k1: per-(b, s-chunk) partial sums + bf16 convert ----
        const int b  = bidx & 7;
        const int sc = bidx >> 3;
        const int i  = t * 4;
        float a0 = 0.f, a1 = 0.f, a2 = 0.f, a3 = 0.f;
        const int s0 = sc * (SDIM / SCH);
        for (int s = s0; s < s0 + (SDIM / SCH); ++s) {
            const float4 v = *reinterpret_cast<const float4*>(
                &x[((size_t)s * BDIM + b) * DIN + i]);
            a0 += v.x; a1 += v.y; a2 += v.z; a3 += v.w;
            ushort4 u{f2bf(v.x), f2bf(v.y), f2bf(v.z), f2bf(v.w)};
            *reinterpret_cast<ushort4*>(&Xb[((size_t)s * BDIM + b) * KAUG + i]) = u;
        }
        float4 p{a0, a1, a2, a3};
        *reinterpret_cast<float4*>(&P[((size_t)sc * BDIM + b) * DIN + i]) = p;
    } else if (bidx < 256 + DOUT) {
        // ---- Waug row ----
        const int o = bidx - 256;
        for (int i = t; i < DIN; i += 256)
            Waug[(size_t)o * KAUG + i] = f2bf(W[(size_t)o * DIN + i]);
        if (t < EDIM * RDIM) {
            const int e = t >> 4, r = t & 15;
            Waug[(size_t)o * KAUG + DIN + t] =
                f2bf(lb[((size_t)e * DOUT + o) * RDIM + r]);
        }
    } else {
        // ---- LAb chunk ----
        const int idx = (bidx - 256 - DOUT) * 256 + t;
        if (idx < EDIM * RDIM * DIN) LAb[idx] = f2bf(la[idx]);
    }
}

// ---------------------------------------------------------------------------
// k2: gate weights (consumes P -> must follow kprep)
// ---------------------------------------------------------------------------
__global__ __launch_bounds__(256) void k2_gates(
    const float* __restrict__ P, const float* __restrict__ gw,
    const float* __restrict__ gb, float* __restrict__ g)
{
    const int e = blockIdx.x, b = blockIdx.y, t = threadIdx.x;
    float dot = 0.f;
    for (int i = t; i < DIN; i += 256) {
        float xs = 0.f;
        #pragma unroll
        for (int c = 0; c < SCH; ++c) xs += P[((size_t)c * BDIM + b) * DIN + i];
        dot += xs * gw[(size_t)e * DIN + i];
    }
    __shared__ float red[256];
    red[t] = dot;
    __syncthreads();
    #pragma unroll
    for (int off = 128; off > 0; off >>= 1) {
        if (t < off) red[t] += red[t + off];
        __syncthreads();
    }
    if (t == 0) g[b * EDIM + e] = red[0] * (1.0f / SDIM) + gb[e];
}

// ---------------------------------------------------------------------------
// gemm_lora2: t = Xb(:, :1024) * LAb^T with fused u = bf16(g*t) epilogue
// written into Xb cols [1024,1152). Tile M=64 x N=128, grid 256 blocks,
// 256 thr / 4 waves (2M x 2N, per-wave 32x64). R6 coalesced+XOR LDS layout.
// LDS 24KB -> multiple blocks/CU. Reads cols <1024, writes >=1024: no race.
// ---------------------------------------------------------------------------
__global__ __launch_bounds__(256) void gemm_lora2(
    const u16* __restrict__ A, const u16* __restrict__ B,
    const float* __restrict__ G, u16* __restrict__ Xb)
{
    __shared__ __align__(16) u16 As[64][64];     // 8 KB
    __shared__ __align__(16) u16 Bs[128][64];    // 16 KB

    const int tid  = threadIdx.x;
    const int lane = tid & 63;
    const int l15  = lane & 15;
    const int l4   = lane >> 4;
    const int sw   = lane & 7;
    const int wid  = tid >> 6;      // 0..3
    const int wr   = wid >> 1;      // 0..1 (32-row slice)
    const int wc   = wid & 1;       // 0..1 (64-col slice)
    const int m0 = blockIdx.y * 64;

    f32x4 acc[2][4] = {};

    for (int kt = 0; kt < DIN / 64; ++kt) {
        #pragma unroll
        for (int ii = 0; ii < 2; ++ii) {
            const int cix = ii * 256 + tid;
            const int row = cix >> 3, cl = cix & 7;
            const int kof = kt * 64 + ((cl ^ (row & 7)) << 3);
            gload16(A + (size_t)(m0 + row) * KAUG + kof, &As[0][0] + cix * 8);
        }
        #pragma unroll
        for (int ii = 0; ii < 4; ++ii) {
            const int cix = ii * 256 + tid;
            const int row = cix >> 3, cl = cix & 7;
            const int kof = kt * 64 + ((cl ^ (row & 7)) << 3);
            gload16(B + (size_t)row * DIN + kof, &Bs[0][0] + cix * 8);
        }
        __syncthreads();
        #pragma unroll
        for (int ks = 0; ks < 2; ++ks) {
            bf16x8 av[2], bv[4];
            #pragma unroll
            for (int mi = 0; mi < 2; ++mi)
                av[mi] = *reinterpret_cast<const bf16x8*>(
                    &As[wr * 32 + mi * 16 + l15][((ks * 4 + l4) ^ sw) << 3]);
            #pragma unroll
            for (int ni = 0; ni < 4; ++ni)
                bv[ni] = *reinterpret_cast<const bf16x8*>(
                    &Bs[wc * 64 + ni * 16 + l15][((ks * 4 + l4) ^ sw) << 3]);
            #pragma unroll
            for (int mi = 0; mi < 2; ++mi)
                #pragma unroll
                for (int ni = 0; ni < 4; ++ni)
                    acc[mi][ni] = __builtin_amdgcn_mfma_f32_16x16x32_bf16(
                        av[mi], bv[ni], acc[mi][ni], 0, 0, 0);
        }
        __syncthreads();
    }

    #pragma unroll
    for (int mi = 0; mi < 2; ++mi) {
        const int r0 = m0 + wr * 32 + mi * 16 + l4 * 4;
        #pragma unroll
        for (int ni = 0; ni < 4; ++ni) {
            const int col = wc * 64 + ni * 16 + l15;   // 0..127
            const int e   = col >> 4;
            #pragma unroll
            for (int r = 0; r < 4; ++r) {
                const int row = r0 + r;
                const float gv = G[((row & 7) << 3) + e];
                Xb[(size_t)row * KAUG + DIN + col] = f2bf(gv * acc[mi][ni][r]);
            }
        }
    }
}

// ---------------------------------------------------------------------------
// gemm_main (FROZEN, best measured: 168-170 us, 909 TF): R8 4-phase
// 1-barrier counted-vmcnt schedule + coalesced staging + (row&7) chunk-XOR
// swizzle + supertile XCD mapping (FETCH 166->110 MB).
// BM=BN=256, BK=64, NT2=18, 512 thr (8 waves 2Mx4N), dbuf LDS 128 KiB.
// Variants measured and rejected: R9 read-ahead 170, R10 2-barrier 178,
// R13 deep-lead 186, R14 B-in-regs 187, R15 min-sync 194.
// ---------------------------------------------------------------------------
__global__ __launch_bounds__(512) void gemm_main(
    const u16* __restrict__ A, const u16* __restrict__ Bm,
    float* __restrict__ C, const float* __restrict__ bias)
{
    __shared__ __align__(16) u16 As[2][2][128][64];   // [buf][Mhalf][row][k] 64 KiB
    __shared__ __align__(16) u16 Bs[2][2][128][64];   // [buf][Nhalf][row][k] 64 KiB

    const int tid  = threadIdx.x;
    const int lane = tid & 63;
    const int l15  = lane & 15;
    const int l4   = lane >> 4;
    const int sw   = lane & 7;
    const int wid  = tid >> 6;      // 0..7
    const int wm   = wid >> 2;      // 0..1  (128-row half)
    const int wn   = wid & 3;       // 0..3  (64-col quarter)
    const int bh   = wn >> 1;       // B Nhalf
    const int bl   = wn & 1;        // 64-row block within half

    // supertile XCD mapping (R12-verified)
    const int f   = blockIdx.x + blockIdx.y * gridDim.x;
    const int xcd = f & 7, k = f >> 3;
    const int gn  = xcd & 3, gm = xcd >> 2;
    const int n0  = (gn * 4 + (k & 3)) * 256;
    const int m0  = (gm * 32 + (k >> 2)) * 256;

    f32x4  acc[8][4] = {};
    bf16x8 aq[2][2], bv[4][2];

    auto stage = [&](int s) {
        const int t = s >> 2, part = s & 3, buf = t & 1, hf = part & 1;
        #pragma unroll
        for (int ii = 0; ii < 2; ++ii) {
            const int cix = ii * 512 + tid;
            const int row = cix >> 3, cl = cix & 7;
            const int kof = t * 64 + ((cl ^ (row & 7)) << 3);
            if (part < 2)
                gload16(A + (size_t)(m0 + hf * 128 + row) * KAUG + kof,
                        &As[buf][hf][0][0] + cix * 8);
            else
                gload16(Bm + (size_t)(n0 + hf * 128 + row) * KAUG + kof,
                        &Bs[buf][hf][0][0] + cix * 8);
        }
    };

    // prologue: units 0..4 (tile 0 fully + A-h0 of tile 1) = 10 gloads
    stage(0); stage(1); stage(2); stage(3); stage(4);
    VMCNT(2);                       // confirm units 0..3 (tile 0); unit 4 in flight
    BARF();

    #define PHASE(P)                                                            \
    do {                                                                        \
        if ((P) == 0) {                                                         \
            _Pragma("unroll") for (int nf = 0; nf < 4; ++nf)                    \
                _Pragma("unroll") for (int kk = 0; kk < 2; ++kk)                \
                    bv[nf][kk] = *reinterpret_cast<const bf16x8*>(              \
                        &Bs[buf][bh][bl * 64 + nf * 16 + l15]                   \
                           [((kk * 4 + l4) ^ sw) << 3]);                        \
        }                                                                       \
        _Pragma("unroll") for (int fr = 0; fr < 2; ++fr)                        \
            _Pragma("unroll") for (int kk = 0; kk < 2; ++kk)                    \
                aq[fr][kk] = *reinterpret_cast<const bf16x8*>(                  \
                    &As[buf][wm][(P) * 32 + fr * 16 + l15]                      \
                       [((kk * 4 + l4) ^ sw) << 3]);                            \
        { const int su = 4 * j + 5 + (P); if (su < 4 * NT2) stage(su); }        \
        __builtin_amdgcn_s_setprio(1);                                          \
        _Pragma("unroll") for (int kk = 0; kk < 2; ++kk)                        \
            _Pragma("unroll") for (int fr = 0; fr < 2; ++fr)                    \
                _Pragma("unroll") for (int nf = 0; nf < 4; ++nf)                \
                    acc[(P) * 2 + fr][nf] =                                     \
                        __builtin_amdgcn_mfma_f32_16x16x32_bf16(                \
                            aq[fr][kk], bv[nf][kk], acc[(P) * 2 + fr][nf],      \
                            0, 0, 0);                                           \
        __builtin_amdgcn_s_setprio(0);                                          \
        if ((P) == 3) { if (j < NT2 - 2) VMCNT(2); else VMCNT(0); }             \
        BARF();                                                                 \
    } while (0)

    for (int j = 0; j < NT2; ++j) {
        const int buf = j & 1;
        PHASE(0);
        PHASE(1);
        PHASE(2);
        PHASE(3);
    }
    #undef PHASE

    // ---- epilogue: row = wm*128 + a*16 + l4*4, col per fragment ----
    #pragma unroll
    for (int a = 0; a < 8; ++a) {
        const int row0 = m0 + wm * 128 + a * 16 + l4 * 4;
        #pragma unroll
        for (int nf = 0; nf < 4; ++nf) {
            const int col = n0 + wn * 64 + nf * 16 + l15;
            const float badd = bias[col];
            float* cp = C + (size_t)row0 * DOUT + col;
            #pragma unroll
            for (int q = 0; q < 4; ++q)
                cp[(size_t)q * DOUT] = acc[a][nf][q] + badd;
        }
    }
}

// ---------------------------------------------------------------------------
extern "C" void kernel_launch(void* const* d_in, const int* in_sizes, int n_in,
                              void* d_out, int out_size, void* d_ws, size_t ws_size,
                              hipStream_t stream)
{
    const float* x    = (const float*)d_in[0];
    const float* gw   = (const float*)d_in[1];
    const float* gb   = (const float*)d_in[2];
    const float* W    = (const float*)d_in[3];
    const float* bias = (const float*)d_in[4];
    const float* la   = (const float*)d_in[5];
    const float* lb   = (const float*)d_in[6];
    float* out = (float*)d_out;

    char* ws = (char*)d_ws;
    u16*   Xb   = (u16*)(ws);                       // 37,748,736 B
    u16*   Waug = (u16*)(ws + 37748736);            //  9,437,184 B
    float* P    = (float*)(ws + 47185920);          //  1,048,576 B
    u16*   LAb  = (u16*)(ws + 48234496);            //    262,144 B
    float* G    = (float*)(ws + 48496640);          //        256 B

    // 1) fused prep: k1 (x reduce+convert) + Waug + LAb  (independent halves)
    kprep<<<256 + DOUT + 512, 256, 0, stream>>>(
        x, Xb, P, W, lb, la, Waug, LAb);
    // 2) gates (consumes P)
    k2_gates<<<dim3(EDIM, BDIM), 256, 0, stream>>>(P, gw, gb, G);
    // 3) LoRA GEMM with fused g-scale epilogue
    gemm_lora2<<<dim3(1, MDIM / 64), 256, 0, stream>>>(Xb, LAb, G, Xb);
    // 4) main GEMM (frozen)
    gemm_main<<<dim3(DOUT / 256, MDIM / 256), 512, 0, stream>>>(
        Xb, Waug, out, bias);
}